// Round 6
// baseline (212.613 us; speedup 1.0000x reference)
//
#include <hip/hip_runtime.h>

// DHSMoEDetector: N=16384 tokens, D=768, H=768, C=2, E=20
#define N_D 768
#define N_H 768
#define N_C 2
#define N_E 20
#define MT 128
#define NT 128
#define BK 32
#define KT (N_D / BK)
#define MAX_TILES 160
#define NCOL (N_H / NT)  // 6 column blocks
#define ROWB (N_D * 2)   // row stride in bytes (bf16)
#define W1BLKS (N_E * (N_D / 64) * (N_H / 64))  // 2880 w1-convert blocks
#define XBBLKS 256                              // token-order convert blocks

typedef __attribute__((ext_vector_type(8))) short short8;
typedef __attribute__((ext_vector_type(4))) float f32x4;

__device__ __forceinline__ unsigned short f2bf(float f) {
  unsigned u = __builtin_bit_cast(unsigned, f);
  u += 0x7FFFu + ((u >> 16) & 1u);
  return (unsigned short)(u >> 16);
}

#define GLD_LDS16(gp, lp)                                                        \
  __builtin_amdgcn_global_load_lds(                                              \
      (const __attribute__((address_space(1))) void*)(gp),                       \
      (__attribute__((address_space(3))) void*)(lp), 16, 0, 0)

// ---------------- D1: everything before the GEMM, one dispatch -------------
// block 0           : hist -> scan -> scatter (sorted[] index list only)
// blocks [1,1+W1B)  : W1 (E,D,H) fp32 -> W1t (E,H,D) bf16, XCD-chunked
// blocks [1+W1B,..) : emb fp32 -> Xb bf16 IN TOKEN ORDER (coalesced both
//                     sides, no dependency on block 0) + out[] zeroing.
// The gather-into-sorted-order is gone: k_gemm reads A rows through
// sorted[] with per-lane global_load_lds source addresses.

__global__ __launch_bounds__(256) void k_prep(
    const int* __restrict__ cidx, int* __restrict__ counts,
    int* __restrict__ offsets, int* __restrict__ tiles,
    int* __restrict__ numTiles, int* __restrict__ sorted,
    const float* __restrict__ emb, unsigned short* __restrict__ Xb,
    const float* __restrict__ W1, unsigned short* __restrict__ W1t,
    float* __restrict__ out, int n) {
  const int tid = threadIdx.x;

  if (blockIdx.x == 0) {
    // ---- front: histogram + scan + tile list + scatter ----
    __shared__ int lc[4][N_E];
    __shared__ int tot[N_E];
    __shared__ int scur[N_E];
    const int w = tid >> 6;
    for (int k = tid; k < 4 * N_E; k += 256) ((int*)lc)[k] = 0;
    __syncthreads();
    const int4* c4 = (const int4*)cidx;
    const int nv = n >> 2;
    for (int i = tid; i < nv; i += 256) {
      int4 v = c4[i];
      int e0 = v.x < 0 ? 0 : (v.x >= N_E ? N_E - 1 : v.x);
      int e1 = v.y < 0 ? 0 : (v.y >= N_E ? N_E - 1 : v.y);
      int e2 = v.z < 0 ? 0 : (v.z >= N_E ? N_E - 1 : v.z);
      int e3 = v.w < 0 ? 0 : (v.w >= N_E ? N_E - 1 : v.w);
      atomicAdd(&lc[w][e0], 1);
      atomicAdd(&lc[w][e1], 1);
      atomicAdd(&lc[w][e2], 1);
      atomicAdd(&lc[w][e3], 1);
    }
    for (int i = (nv << 2) + tid; i < n; i += 256) {
      int e = cidx[i];
      e = e < 0 ? 0 : (e >= N_E ? N_E - 1 : e);
      atomicAdd(&lc[w][e], 1);
    }
    __syncthreads();
    if (tid < N_E) tot[tid] = lc[0][tid] + lc[1][tid] + lc[2][tid] + lc[3][tid];
    __syncthreads();
    if (tid < 64) {
      int lane = tid;
      int c = (lane < N_E) ? tot[lane] : 0;
      int nt = (c + MT - 1) / MT;
      int cs = c, ts = nt;
#pragma unroll
      for (int s = 1; s < 32; s <<= 1) {
        int t1 = __shfl_up(cs, s, 64);
        int t2 = __shfl_up(ts, s, 64);
        if (lane >= s) {
          cs += t1;
          ts += t2;
        }
      }
      int coff = cs - c;
      int tbase = ts - nt;
      if (lane < N_E) {
        counts[lane] = c;
        offsets[lane] = coff;
        scur[lane] = coff;
        for (int m = 0; m < nt; ++m) {
          int t = tbase + m;
          if (t < MAX_TILES) tiles[t] = (lane << 8) | m;
        }
      }
      if (lane == N_E - 1) *numTiles = ts > MAX_TILES ? MAX_TILES : ts;
    }
    __syncthreads();
    // scatter: any intra-expert order is valid (output keyed by token id)
    for (int i = tid; i < n; i += 256) {
      int e = cidx[i];
      e = e < 0 ? 0 : (e >= N_E ? N_E - 1 : e);
      int p = atomicAdd(&scur[e], 1);
      sorted[p] = i;
    }
    return;
  }

  if ((int)blockIdx.x < 1 + W1BLKS) {
    // ---- W1 convert/transpose with bijective XCD chunk remap ----
    __shared__ float tile[64][65];
    int w1i = blockIdx.x - 1;
    int xcd = w1i & 7, ii = w1i >> 3;
    int wgid = xcd * (W1BLKS / 8) + ii;
    int e = wgid / 144;
    int rem = wgid - e * 144;
    int h0 = (rem % 12) * 64, d0 = (rem / 12) * 64;
    const float* src = W1 + (size_t)e * N_D * N_H;
    unsigned short* dst = W1t + (size_t)e * N_H * N_D;
    int tx = tid & 15, ty = tid >> 4;
#pragma unroll
    for (int s = 0; s < 4; ++s) {
      int d = s * 16 + ty;
      float4 v = *(const float4*)&src[(size_t)(d0 + d) * N_H + h0 + tx * 4];
      tile[d][tx * 4 + 0] = v.x;
      tile[d][tx * 4 + 1] = v.y;
      tile[d][tx * 4 + 2] = v.z;
      tile[d][tx * 4 + 3] = v.w;
    }
    __syncthreads();
    int px = tid & 7, py = tid >> 3;
#pragma unroll
    for (int s = 0; s < 2; ++s) {
      int h = s * 32 + py;
      short8 v;
#pragma unroll
      for (int j = 0; j < 8; ++j)
        v[j] = (short)f2bf(tile[px * 8 + j][h]);
      *(short8*)&dst[(size_t)(h0 + h) * N_D + d0 + px * 8] = v;
    }
    return;
  }

  // ---- token-order fp32 -> bf16 convert (fully coalesced) + out zero ----
  int xb = blockIdx.x - 1 - W1BLKS;  // 0..XBBLKS-1
  const float4* s4 = (const float4*)emb;
  ushort4* d4 = (ushort4*)Xb;
  const int total = n * (N_D / 4);
  for (int k = xb * 256 + tid; k < total; k += XBBLKS * 256) {
    float4 v = s4[k];
    ushort4 o;
    o.x = f2bf(v.x);
    o.y = f2bf(v.y);
    o.z = f2bf(v.z);
    o.w = f2bf(v.w);
    d4[k] = o;
  }
  if (xb < 8) {
    float4 zf = {0.f, 0.f, 0.f, 0.f};
    float4* of = (float4*)out;
    for (int k = xb * 256 + tid; k < n * N_C / 4; k += 8 * 256) of[k] = zf;
  }
}

// ---------------- D2: fused grouped GEMM1 + relu + layer2 ------------------
// Round-1 proven loop (depth-2 LDS pipeline, chunk-major conflict-free
// staging, XCD chunk swizzle, launch_bounds(256,2)). Only change: A rows are
// gathered THROUGH sorted[] via per-lane global_load_lds source addresses
// (LDS dest stays linear). Tail positions clamp to token 0; their outputs
// are masked by cnt_rel as before.

__global__ __launch_bounds__(256, 2) void k_gemm(
    const unsigned short* __restrict__ Xb, const unsigned short* __restrict__ W1t,
    const float* __restrict__ b1, const float* __restrict__ W2,
    const float* __restrict__ b2, const int* __restrict__ sorted,
    const int* __restrict__ counts, const int* __restrict__ offsets,
    const int* __restrict__ tiles, const int* __restrict__ numTiles,
    float* __restrict__ out, int n) {
  const int nactive = *numTiles * NCOL;
  const int lin = (int)blockIdx.y * NCOL + (int)blockIdx.x;
  if (lin >= nactive) return;
  const int q = nactive >> 3, r = nactive & 7;
  const int c = lin & 7, ii = lin >> 3;
  const int wgid = (c < r ? c * (q + 1) : r * (q + 1) + (c - r) * q) + ii;
  const int tileIdx = wgid / NCOL;
  const int n0 = (wgid - tileIdx * NCOL) * NT;

  const int tv = tiles[tileIdx];
  const int e = tv >> 8;
  const int m0 = (tv & 255) * MT;
  const int off = offsets[e];
  const int cnt_rel = counts[e] - m0;

  __shared__ unsigned short lA[2][MT * BK];  // 2 x 8KB, chunk-major groups
  __shared__ unsigned short lB[2][NT * BK];

  const int tid = threadIdx.x;
  const int wid = tid >> 6, lane = tid & 63;
  const int wm = (wid >> 1) * 64, wn = (wid & 1) * 64;
  const int quad = lane >> 4, lm = lane & 15;

  const int R0 = wid * 32 + lm;
  // A row indirection: token ids for this lane's two staged rows
  const int pos0 = off + m0 + R0;
  const int pos1 = pos0 + 16;
  const int t0 = sorted[pos0 < n ? pos0 : 0];
  const int t1 = sorted[pos1 < n ? pos1 : 0];
  const char* agp0 = (const char*)Xb + (size_t)t0 * ROWB + quad * 16;
  const char* agp1 = (const char*)Xb + (size_t)t1 * ROWB + quad * 16;
  const char* bgp = (const char*)W1t + (size_t)e * N_H * ROWB +
                    (size_t)(n0 + R0) * ROWB + quad * 16;
  unsigned short* lap[2] = {&lA[0][(wid * 32) * BK], &lA[1][(wid * 32) * BK]};
  unsigned short* lbp[2] = {&lB[0][(wid * 32) * BK], &lB[1][(wid * 32) * BK]};

#define ISSUE_BATCH(kk, b)                                                       \
  do {                                                                           \
    const char* b_ = bgp + (kk)*64;                                              \
    GLD_LDS16(agp0 + (kk)*64, lap[b]);                                           \
    GLD_LDS16(agp1 + (kk)*64, lap[b] + 16 * BK);                                 \
    GLD_LDS16(b_, lbp[b]);                                                       \
    GLD_LDS16(b_ + 16 * ROWB, lbp[b] + 16 * BK);                                 \
  } while (0)

  f32x4 acc[4][4] = {};

  ISSUE_BATCH(0, 0);
  ISSUE_BATCH(1, 1);

  const int fa = quad * 128 + lm * 8;

  for (int kt = 0; kt < KT; ++kt) {
    const int cur = kt & 1;
    asm volatile("s_waitcnt vmcnt(4)\n\ts_barrier" ::: "memory");
    short8 af[4], bfr[4];
    for (int i = 0; i < 4; ++i)
      af[i] = *(const short8*)&lA[cur][((wm >> 4) + i) * 512 + fa];
    for (int j = 0; j < 4; ++j)
      bfr[j] = *(const short8*)&lB[cur][((wn >> 4) + j) * 512 + fa];
    asm volatile("s_waitcnt lgkmcnt(0)\n\ts_barrier" ::: "memory");
    int kk = kt + 2;
    if (kk >= KT) kk -= KT;  // dummy re-load keeps vmcnt bookkeeping uniform
    ISSUE_BATCH(kk, cur);
    for (int i = 0; i < 4; ++i)
      for (int j = 0; j < 4; ++j)
        acc[i][j] =
            __builtin_amdgcn_mfma_f32_16x16x32_bf16(af[i], bfr[j], acc[i][j], 0, 0, 0);
  }

  // ---- fused epilogue: h = relu(acc + b1), y-partial = h * W2[e] ----
  float y0[4][4], y1[4][4];
  for (int i = 0; i < 4; ++i)
    for (int r2 = 0; r2 < 4; ++r2) y0[i][r2] = y1[i][r2] = 0.f;

  for (int j = 0; j < 4; ++j) {
    int col = n0 + wn + j * 16 + lm;
    float bias = b1[e * N_H + col];
    float2 w2 = *(const float2*)&W2[((size_t)e * N_H + col) * N_C];
    for (int i = 0; i < 4; ++i) {
      f32x4 a = acc[i][j];
      for (int r2 = 0; r2 < 4; ++r2) {
        float h = a[r2] + bias;
        h = h > 0.f ? h : 0.f;
        y0[i][r2] += h * w2.x;
        y1[i][r2] += h * w2.y;
      }
    }
  }
  for (int s = 1; s < 16; s <<= 1) {
    for (int i = 0; i < 4; ++i)
      for (int r2 = 0; r2 < 4; ++r2) {
        y0[i][r2] += __shfl_xor(y0[i][r2], s, 64);
        y1[i][r2] += __shfl_xor(y1[i][r2], s, 64);
      }
  }
  if (lm == 0) {
    const bool add_bias = (n0 == 0) && (wn == 0);
    float bb0 = add_bias ? b2[e * N_C + 0] : 0.f;
    float bb1 = add_bias ? b2[e * N_C + 1] : 0.f;
    for (int i = 0; i < 4; ++i) {
      for (int r2 = 0; r2 < 4; ++r2) {
        int mrel = wm + i * 16 + quad * 4 + r2;
        if (mrel < cnt_rel) {
          int token = sorted[off + m0 + mrel];
          atomicAdd(&out[(size_t)token * N_C + 0], y0[i][r2] + bb0);
          atomicAdd(&out[(size_t)token * N_C + 1], y1[i][r2] + bb1);
        }
      }
    }
  }
}

// ---------------- launch ----------------

extern "C" void kernel_launch(void* const* d_in, const int* in_sizes, int n_in,
                              void* d_out, int out_size, void* d_ws, size_t ws_size,
                              hipStream_t stream) {
  const float* emb = (const float*)d_in[0];
  const int* cidx = (const int*)d_in[1];
  const float* W1 = (const float*)d_in[2];
  const float* b1 = (const float*)d_in[3];
  const float* W2 = (const float*)d_in[4];
  const float* b2 = (const float*)d_in[5];
  float* out = (float*)d_out;
  const int n = in_sizes[1];

  char* ws = (char*)d_ws;
  int* counts = (int*)ws;
  int* offsets = (int*)(ws + 128);
  int* numTiles = (int*)(ws + 384);
  int* tiles = (int*)(ws + 512);
  int* sorted = (int*)(ws + 2048);
  size_t sorted_bytes = ((size_t)n * 4 + 255) & ~(size_t)255;
  unsigned short* Xb = (unsigned short*)(ws + 2048 + sorted_bytes);
  unsigned short* W1t = Xb + (size_t)n * N_D;

  // 2 dispatches, no memsets. All workspace state rewritten every call.
  k_prep<<<1 + W1BLKS + XBBLKS, 256, 0, stream>>>(
      cidx, counts, offsets, tiles, numTiles, sorted, emb, Xb, W1, W1t, out, n);
  k_gemm<<<dim3(NCOL, MAX_TILES), 256, 0, stream>>>(
      Xb, W1t, b1, W2, b2, sorted, counts, offsets, tiles, numTiles, out, n);
}